// Round 2
// baseline (2197.917 us; speedup 1.0000x reference)
//
#include <hip/hip_runtime.h>

#define Hdim 256
#define Bdim 16
#define Lleaf 4096

#define BM 64
#define BN 64
#define BK 16
#define TM 4
#define TN 4
// 256 threads/block = (BM/TM)*(BN/TN)

__device__ __forceinline__ float sigmoidf_(float x) { return 1.0f / (1.0f + expf(-x)); }

// ---------------- leaf: h0 = emb[ids] @ Wp + bp  (c0 NOT stored; c0=tanh(h0) on the fly later)
__global__ __launch_bounds__(256) void gemm_leaf(
    const int* __restrict__ ids, const float* __restrict__ emb,
    const float* __restrict__ Wp, const float* __restrict__ bp,
    float* __restrict__ h0, int M)
{
    const int K = 256;
    int m0 = blockIdx.y * BM;
    int n0 = blockIdx.x * BN;

    __shared__ float As[BK][BM + 1];
    __shared__ float Bs[BK][BN];

    int tid = threadIdx.x;
    int arow = tid >> 2;           // 0..63
    int akq  = (tid & 3) << 2;     // 0,4,8,12
    int brow = tid >> 4;           // 0..15
    int bcol = (tid & 15) << 2;    // 0..60
    int ty = tid >> 4;             // 0..15
    int tx = tid & 15;

    float acc[TM][TN];
#pragma unroll
    for (int i = 0; i < TM; i++)
#pragma unroll
        for (int j = 0; j < TN; j++) acc[i][j] = 0.f;

    int gm = m0 + arow;
    const float* arow_ptr = nullptr;
    if (gm < M) arow_ptr = emb + (size_t)ids[gm] * K;

    for (int k0 = 0; k0 < K; k0 += BK) {
        float4 av = make_float4(0, 0, 0, 0);
        if (arow_ptr) av = *(const float4*)(arow_ptr + k0 + akq);
        As[akq + 0][arow] = av.x; As[akq + 1][arow] = av.y;
        As[akq + 2][arow] = av.z; As[akq + 3][arow] = av.w;
        float4 bv = *(const float4*)(Wp + (size_t)(k0 + brow) * Hdim + n0 + bcol);
        *(float4*)(&Bs[brow][bcol]) = bv;
        __syncthreads();
#pragma unroll
        for (int k = 0; k < BK; k++) {
            float a[TM], b[TN];
#pragma unroll
            for (int i = 0; i < TM; i++) a[i] = As[k][ty * TM + i];
#pragma unroll
            for (int j = 0; j < TN; j++) b[j] = Bs[k][tx * TN + j];
#pragma unroll
            for (int i = 0; i < TM; i++)
#pragma unroll
                for (int j = 0; j < TN; j++) acc[i][j] += a[i] * b[j];
        }
        __syncthreads();
    }
#pragma unroll
    for (int i = 0; i < TM; i++) {
        int om = m0 + ty * TM + i;
        if (om < M) {
            int oc = n0 + tx * TN;
            size_t base = (size_t)om * Hdim + oc;
#pragma unroll
            for (int j = 0; j < TN; j++)
                h0[base + j] = acc[i][j] + bp[oc + j];
        }
    }
}

// ---------------- fused level: all 5 gate GEMMs + LSTM combine in one kernel ----------------
// h_in viewed as (M x 512): row m = [h_prev[2m] | h_prev[2m+1]] (contiguous in memory).
// leafmode: children c = tanh(h_child) read from h_in; else c_in is (2M x 256).
__global__ __launch_bounds__(256) void level_fused(
    const float* __restrict__ Hin, const float* __restrict__ Cin,
    const float* __restrict__ Wfl, const float* __restrict__ Wfr,
    const float* __restrict__ Wi,  const float* __restrict__ Wo,
    const float* __restrict__ Wc,
    const float* __restrict__ bfl, const float* __restrict__ bfr,
    const float* __restrict__ bi,  const float* __restrict__ bo,
    const float* __restrict__ bc,
    float* __restrict__ Hout, float* __restrict__ Cout,
    int M, int leafmode)
{
    const int K = 512;
    int m0 = blockIdx.y * BM;
    int n0 = blockIdx.x * BN;

    __shared__ float As[BK][BM + 1];        // 4.2 KB
    __shared__ float Bs[5][BK][BN];         // 20 KB

    int tid = threadIdx.x;
    int arow = tid >> 2;           // 0..63
    int akq  = (tid & 3) << 2;     // 0,4,8,12
    int brow = tid >> 4;           // 0..15
    int bcol = (tid & 15) << 2;    // 0..60
    int ty = tid >> 4;
    int tx = tid & 15;

    const float* Ws[5] = {Wfl, Wfr, Wi, Wo, Wc};

    float acc[5][TM][TN];
#pragma unroll
    for (int g = 0; g < 5; g++)
#pragma unroll
        for (int i = 0; i < TM; i++)
#pragma unroll
            for (int j = 0; j < TN; j++) acc[g][i][j] = 0.f;

    int gm = m0 + arow;
    const float* arow_ptr = (gm < M) ? (Hin + (size_t)gm * K) : nullptr;

    for (int k0 = 0; k0 < K; k0 += BK) {
        float4 av = make_float4(0, 0, 0, 0);
        if (arow_ptr) av = *(const float4*)(arow_ptr + k0 + akq);
        As[akq + 0][arow] = av.x; As[akq + 1][arow] = av.y;
        As[akq + 2][arow] = av.z; As[akq + 3][arow] = av.w;
#pragma unroll
        for (int g = 0; g < 5; g++) {
            float4 bv = *(const float4*)(Ws[g] + (size_t)(k0 + brow) * Hdim + n0 + bcol);
            *(float4*)(&Bs[g][brow][bcol]) = bv;
        }
        __syncthreads();
#pragma unroll
        for (int k = 0; k < BK; k++) {
            float a[TM];
#pragma unroll
            for (int i = 0; i < TM; i++) a[i] = As[k][ty * TM + i];
#pragma unroll
            for (int g = 0; g < 5; g++) {
                float b[TN];
#pragma unroll
                for (int j = 0; j < TN; j++) b[j] = Bs[g][k][tx * TN + j];
#pragma unroll
                for (int i = 0; i < TM; i++)
#pragma unroll
                    for (int j = 0; j < TN; j++) acc[g][i][j] += a[i] * b[j];
            }
        }
        __syncthreads();
    }

    // epilogue: gates -> c_out, h_out
#pragma unroll
    for (int i = 0; i < TM; i++) {
        int om = m0 + ty * TM + i;
        if (om >= M) continue;
#pragma unroll
        for (int j = 0; j < TN; j++) {
            int n = n0 + tx * TN + j;
            float fl = sigmoidf_(acc[0][i][j] + bfl[n]);
            float fr = sigmoidf_(acc[1][i][j] + bfr[n]);
            float ig = sigmoidf_(acc[2][i][j] + bi[n]);
            float og = sigmoidf_(acc[3][i][j] + bo[n]);
            float cc = tanhf(acc[4][i][j] + bc[n]);
            float cl, cr;
            if (leafmode) {
                cl = tanhf(Hin[(size_t)om * 512 + n]);
                cr = tanhf(Hin[(size_t)om * 512 + 256 + n]);
            } else {
                cl = Cin[(size_t)(2 * om) * Hdim + n];
                cr = Cin[(size_t)(2 * om + 1) * Hdim + n];
            }
            float cn = fl * cl + fr * cr + ig * cc;
            size_t idx = (size_t)om * Hdim + n;
            Cout[idx] = cn;
            Hout[idx] = og * tanhf(cn);
        }
    }
}

// ---------------- classifier ----------------
__global__ void classifier(const float* __restrict__ hroot, const float* __restrict__ Wcls,
                           const float* __restrict__ bcls, float* __restrict__ out)
{
    int t = threadIdx.x;
    if (t < Bdim * 2) {
        int b = t >> 1, cls = t & 1;
        float s = bcls[cls];
        for (int j = 0; j < Hdim; j++) s += hroot[b * Hdim + j] * Wcls[j * 2 + cls];
        out[t] = s;
    }
}

extern "C" void kernel_launch(void* const* d_in, const int* in_sizes, int n_in,
                              void* d_out, int out_size, void* d_ws, size_t ws_size,
                              hipStream_t stream) {
    const int*   ids  = (const int*)d_in[0];
    const float* emb  = (const float*)d_in[1];
    const float* Wp   = (const float*)d_in[2];
    const float* bp   = (const float*)d_in[3];
    const float* Wfl  = (const float*)d_in[4];
    const float* bfl  = (const float*)d_in[5];
    const float* Wfr  = (const float*)d_in[6];
    const float* bfr  = (const float*)d_in[7];
    const float* Wi   = (const float*)d_in[8];
    const float* bi   = (const float*)d_in[9];
    const float* Wo   = (const float*)d_in[10];
    const float* bo   = (const float*)d_in[11];
    const float* Wc   = (const float*)d_in[12];
    const float* bc   = (const float*)d_in[13];
    const float* Wcls = (const float*)d_in[14];
    const float* bcls = (const float*)d_in[15];

    // workspace: exactly 2 x 16,777,216 floats = 128 MiB
    float* r0 = (float*)d_ws;                 // region 0 (leaf h0, then even levels)
    float* r1 = r0 + 16777216;                // region 1 (odd levels)

    int M0 = Bdim * Lleaf;                    // 65536
    dim3 blk(256);
    gemm_leaf<<<dim3(Hdim / BN, M0 / BM), blk, 0, stream>>>(ids, emb, Wp, bp, r0, M0);

    const float* hin = r0;
    const float* cin = nullptr;
    int level = 1;
    for (int Lout = Lleaf / 2; Lout >= 1; Lout >>= 1, level++) {
        int M = Bdim * Lout;                  // 32768 ... 16
        float* base = (level & 1) ? r1 : r0;
        float* hout = base;
        float* cout = base + (size_t)M * Hdim;
        dim3 grid(Hdim / BN, (M + BM - 1) / BM);
        level_fused<<<grid, blk, 0, stream>>>(hin, cin,
                                              Wfl, Wfr, Wi, Wo, Wc,
                                              bfl, bfr, bi, bo, bc,
                                              hout, cout, M, (level == 1) ? 1 : 0);
        hin = hout; cin = cout;
    }
    classifier<<<1, 64, 0, stream>>>(hin, Wcls, bcls, (float*)d_out);
}

// Round 3
// 1521.606 us; speedup vs baseline: 1.4445x; 1.4445x over previous
//
#include <hip/hip_runtime.h>
#include <hip/hip_bf16.h>

#define Hdim 256
#define Bdim 16
#define Lleaf 4096

typedef unsigned short u16;
typedef __attribute__((ext_vector_type(8))) short short8;
typedef __attribute__((ext_vector_type(4))) float f32x4;

__device__ __forceinline__ u16 f2bf(float x) {
    __hip_bfloat16 b = __float2bfloat16(x);
    return *(u16*)&b;
}
__device__ __forceinline__ float bf2f(u16 u) {
    __hip_bfloat16 b = *(__hip_bfloat16*)&u;
    return __bfloat162float(b);
}
__device__ __forceinline__ float fsig(float x) { return 1.0f / (1.0f + __expf(-x)); }
__device__ __forceinline__ float ftanh(float x) {
    float e = __expf(-2.0f * fabsf(x));
    float t = (1.0f - e) / (1.0f + e);
    return copysignf(t, x);
}

// ---------------- weight split+transpose: Wt[g*256+n][k] = W_g[k][n], bf16 hi/lo ----------------
__global__ void split_weights(const float* __restrict__ Wfl, const float* __restrict__ Wfr,
                              const float* __restrict__ Wi,  const float* __restrict__ Wo,
                              const float* __restrict__ Wc,
                              u16* __restrict__ Wthi, u16* __restrict__ Wtlo)
{
    int np = blockIdx.x;            // 0..1279
    int g = np >> 8, n = np & 255;
    const float* W = (g == 0) ? Wfl : (g == 1) ? Wfr : (g == 2) ? Wi : (g == 3) ? Wo : Wc;
    for (int k = threadIdx.x; k < 512; k += 256) {
        float x = W[(size_t)k * Hdim + n];
        u16 hi = f2bf(x);
        u16 lo = f2bf(x - bf2f(hi));
        size_t idx = (size_t)np * 512 + k;
        Wthi[idx] = hi;
        Wtlo[idx] = lo;
    }
}

// ---------------- leaf: h0 = emb[ids] @ Wp + bp, stored as single bf16 in level-1 A layout ------
#define BM 64
#define BN 64
#define BK 16
#define TM 4
#define TN 4
__global__ __launch_bounds__(256) void gemm_leaf(
    const int* __restrict__ ids, const float* __restrict__ emb,
    const float* __restrict__ Wp, const float* __restrict__ bp,
    u16* __restrict__ A0, int M)
{
    const int K = 256;
    int m0 = blockIdx.y * BM;
    int n0 = blockIdx.x * BN;

    __shared__ float As[BK][BM + 1];
    __shared__ float Bs[BK][BN];

    int tid = threadIdx.x;
    int arow = tid >> 2;
    int akq  = (tid & 3) << 2;
    int brow = tid >> 4;
    int bcol = (tid & 15) << 2;
    int ty = tid >> 4;
    int tx = tid & 15;

    float acc[TM][TN];
#pragma unroll
    for (int i = 0; i < TM; i++)
#pragma unroll
        for (int j = 0; j < TN; j++) acc[i][j] = 0.f;

    int gm = m0 + arow;
    const float* arow_ptr = (gm < M) ? (emb + (size_t)ids[gm] * K) : nullptr;

    for (int k0 = 0; k0 < K; k0 += BK) {
        float4 av = make_float4(0, 0, 0, 0);
        if (arow_ptr) av = *(const float4*)(arow_ptr + k0 + akq);
        As[akq + 0][arow] = av.x; As[akq + 1][arow] = av.y;
        As[akq + 2][arow] = av.z; As[akq + 3][arow] = av.w;
        float4 bv = *(const float4*)(Wp + (size_t)(k0 + brow) * Hdim + n0 + bcol);
        *(float4*)(&Bs[brow][bcol]) = bv;
        __syncthreads();
#pragma unroll
        for (int k = 0; k < BK; k++) {
            float a[TM], b[TN];
#pragma unroll
            for (int i = 0; i < TM; i++) a[i] = As[k][ty * TM + i];
#pragma unroll
            for (int j = 0; j < TN; j++) b[j] = Bs[k][tx * TN + j];
#pragma unroll
            for (int i = 0; i < TM; i++)
#pragma unroll
                for (int j = 0; j < TN; j++) acc[i][j] += a[i] * b[j];
        }
        __syncthreads();
    }
#pragma unroll
    for (int i = 0; i < TM; i++) {
        int om = m0 + ty * TM + i;
        if (om < M) {
            int oc = n0 + tx * TN;
#pragma unroll
            for (int j = 0; j < TN; j++) {
                float h = acc[i][j] + bp[oc + j];
                A0[(size_t)(om >> 1) * 512 + (om & 1) * 256 + oc + j] = f2bf(h);
            }
        }
    }
}

// ---------------- fused level: 5 gate GEMMs via MFMA (bf16 split) + LSTM combine ----------------
// A viewed as (M x 512) bf16 (hi [+lo]); Wt is (1280 x 512) bf16 hi/lo, row = g*256+n, k-contig.
// Block: 64m x 64n x 5 gates. 4 waves; wave w -> (m-half = w&1, n-half = w>>1).
// No LDS: fragments load straight from global (k-contiguous rows match MFMA frag layout).
template <int LEAF>
__global__ __launch_bounds__(256) void level_mfma(
    const u16* __restrict__ Ahi, const u16* __restrict__ Alo,
    const float* __restrict__ Cin,
    const u16* __restrict__ Wthi, const u16* __restrict__ Wtlo,
    const float* __restrict__ bfl, const float* __restrict__ bfr,
    const float* __restrict__ bi,  const float* __restrict__ bo,
    const float* __restrict__ bc,
    u16* __restrict__ Aohi, u16* __restrict__ Aolo, float* __restrict__ Cout,
    int M)
{
    int tid = threadIdx.x;
    int lane = tid & 63, wave = tid >> 6;
    int l16 = lane & 15, quad = lane >> 4;
    int mh = wave & 1, nh = wave >> 1;
    int m0 = blockIdx.x * 64, n0 = blockIdx.y * 64;

    int mr0 = m0 + mh * 32 + l16;
    int ar0 = min(mr0, M - 1);
    int ar1 = min(mr0 + 16, M - 1);
    const u16* pa0h = Ahi + (size_t)ar0 * 512 + quad * 8;
    const u16* pa1h = Ahi + (size_t)ar1 * 512 + quad * 8;
    const u16* pa0l = LEAF ? pa0h : (Alo + (size_t)ar0 * 512 + quad * 8);
    const u16* pa1l = LEAF ? pa1h : (Alo + (size_t)ar1 * 512 + quad * 8);

    int ncol = n0 + nh * 32 + l16;                 // n for nt=0 (within 256)
    size_t wb = (size_t)ncol * 512 + quad * 8;     // base elem offset into Wt

    f32x4 acc[5][2][2];
    f32x4 zf = {0.f, 0.f, 0.f, 0.f};
#pragma unroll
    for (int g = 0; g < 5; g++)
#pragma unroll
        for (int i = 0; i < 2; i++)
#pragma unroll
            for (int j = 0; j < 2; j++) acc[g][i][j] = zf;

#pragma unroll 2
    for (int k = 0; k < 512; k += 32) {
        short8 a0h = *(const short8*)(pa0h + k);
        short8 a1h = *(const short8*)(pa1h + k);
        short8 a0l, a1l;
        if (!LEAF) {
            a0l = *(const short8*)(pa0l + k);
            a1l = *(const short8*)(pa1l + k);
        }
#pragma unroll
        for (int g = 0; g < 5; g++) {
#pragma unroll
            for (int nt = 0; nt < 2; nt++) {
                size_t wo = wb + (size_t)g * 131072 + nt * 8192 + k;
                short8 bh = *(const short8*)(Wthi + wo);
                short8 bl = *(const short8*)(Wtlo + wo);
                acc[g][0][nt] = __builtin_amdgcn_mfma_f32_16x16x32_bf16(a0h, bh, acc[g][0][nt], 0, 0, 0);
                acc[g][1][nt] = __builtin_amdgcn_mfma_f32_16x16x32_bf16(a1h, bh, acc[g][1][nt], 0, 0, 0);
                acc[g][0][nt] = __builtin_amdgcn_mfma_f32_16x16x32_bf16(a0h, bl, acc[g][0][nt], 0, 0, 0);
                acc[g][1][nt] = __builtin_amdgcn_mfma_f32_16x16x32_bf16(a1h, bl, acc[g][1][nt], 0, 0, 0);
                if (!LEAF) {
                    acc[g][0][nt] = __builtin_amdgcn_mfma_f32_16x16x32_bf16(a0l, bh, acc[g][0][nt], 0, 0, 0);
                    acc[g][1][nt] = __builtin_amdgcn_mfma_f32_16x16x32_bf16(a1l, bh, acc[g][1][nt], 0, 0, 0);
                }
            }
        }
    }

    // epilogue: C/D frag element r -> (row = quad*4 + r, col = l16)
#pragma unroll
    for (int mt = 0; mt < 2; mt++) {
        int mbase = m0 + mh * 32 + mt * 16 + quad * 4;
#pragma unroll
        for (int r = 0; r < 4; r++) {
            int m = mbase + r;
            if (m >= M) continue;
#pragma unroll
            for (int nt = 0; nt < 2; nt++) {
                int n = n0 + nh * 32 + nt * 16 + l16;
                float fl = fsig(acc[0][mt][nt][r] + bfl[n]);
                float fr = fsig(acc[1][mt][nt][r] + bfr[n]);
                float ig = fsig(acc[2][mt][nt][r] + bi[n]);
                float og = fsig(acc[3][mt][nt][r] + bo[n]);
                float cc = ftanh(acc[4][mt][nt][r] + bc[n]);
                float cl, cr;
                if (LEAF) {
                    cl = ftanh(bf2f(Ahi[(size_t)m * 512 + n]));
                    cr = ftanh(bf2f(Ahi[(size_t)m * 512 + 256 + n]));
                } else {
                    cl = Cin[(size_t)(2 * m) * 256 + n];
                    cr = Cin[(size_t)(2 * m + 1) * 256 + n];
                }
                float cn = fl * cl + fr * cr + ig * cc;
                Cout[(size_t)m * 256 + n] = cn;
                float h = og * ftanh(cn);
                u16 hh = f2bf(h);
                u16 hl = f2bf(h - bf2f(hh));
                size_t ai = (size_t)(m >> 1) * 512 + (m & 1) * 256 + n;
                Aohi[ai] = hh;
                Aolo[ai] = hl;
            }
        }
    }
}

// ---------------- classifier ----------------
__global__ void classifier_bf(const u16* __restrict__ Ahi, const u16* __restrict__ Alo,
                              const float* __restrict__ Wcls, const float* __restrict__ bcls,
                              float* __restrict__ out)
{
    int t = threadIdx.x;
    if (t < Bdim * 2) {
        int b = t >> 1, cls = t & 1;
        float s = bcls[cls];
        for (int n = 0; n < Hdim; n++) {
            size_t ai = (size_t)(b >> 1) * 512 + (b & 1) * 256 + n;
            float h = bf2f(Ahi[ai]) + bf2f(Alo[ai]);
            s += h * Wcls[(size_t)n * 2 + cls];
        }
        out[t] = s;
    }
}

extern "C" void kernel_launch(void* const* d_in, const int* in_sizes, int n_in,
                              void* d_out, int out_size, void* d_ws, size_t ws_size,
                              hipStream_t stream) {
    const int*   ids  = (const int*)d_in[0];
    const float* emb  = (const float*)d_in[1];
    const float* Wp   = (const float*)d_in[2];
    const float* bp   = (const float*)d_in[3];
    const float* Wfl  = (const float*)d_in[4];
    const float* bfl  = (const float*)d_in[5];
    const float* Wfr  = (const float*)d_in[6];
    const float* bfr  = (const float*)d_in[7];
    const float* Wi   = (const float*)d_in[8];
    const float* bi   = (const float*)d_in[9];
    const float* Wo   = (const float*)d_in[10];
    const float* bo   = (const float*)d_in[11];
    const float* Wc   = (const float*)d_in[12];
    const float* bc   = (const float*)d_in[13];
    const float* Wcls = (const float*)d_in[14];
    const float* bcls = (const float*)d_in[15];

    // ---- workspace layout (peak ~105 MB; R2 confirmed >= 128 MiB available) ----
    // [0, 2.62MB)   : Wt hi/lo (1280x512 bf16 each)
    // [4MB, +32MB)  : R1  (leaf A0 / even-level outputs)
    // [4MB+32MB, +64MB) : R2+overflow (odd-level outputs; L1's C spills past R2)
    u16* Wthi = (u16*)d_ws;
    u16* Wtlo = Wthi + (size_t)1280 * 512;
    unsigned char* base = (unsigned char*)d_ws + (4u << 20);
    unsigned char* R1 = base;
    unsigned char* R2 = base + 33554432;

    split_weights<<<1280, 256, 0, stream>>>(Wfl, Wfr, Wi, Wo, Wc, Wthi, Wtlo);

    int M0 = Bdim * Lleaf;  // 65536 leaves
    gemm_leaf<<<dim3(Hdim / BN, M0 / BM), 256, 0, stream>>>(ids, emb, Wp, bp, (u16*)R1, M0);

    const u16* Ain_hi = (const u16*)R1;
    const u16* Ain_lo = nullptr;
    const float* Cin = nullptr;

    int M = 32768;  // output nodes at level 1
    int lev = 1;
    for (; M >= 16; M >>= 1, lev++) {
        unsigned char* ob = (lev & 1) ? R2 : R1;
        u16* Aohi = (u16*)ob;
        u16* Aolo = Aohi + (size_t)M * 256;           // out rows M/2, 512 elems each
        float* Cout = (float*)(Aohi + (size_t)M * 512);
        dim3 grid(M >= 64 ? M / 64 : 1, Hdim / 64);
        if (lev == 1)
            level_mfma<1><<<grid, 256, 0, stream>>>(Ain_hi, nullptr, nullptr, Wthi, Wtlo,
                                                    bfl, bfr, bi, bo, bc, Aohi, Aolo, Cout, M);
        else
            level_mfma<0><<<grid, 256, 0, stream>>>(Ain_hi, Ain_lo, Cin, Wthi, Wtlo,
                                                    bfl, bfr, bi, bo, bc, Aohi, Aolo, Cout, M);
        Ain_hi = Aohi; Ain_lo = Aolo; Cin = Cout;
    }

    classifier_bf<<<1, 64, 0, stream>>>(Ain_hi, Ain_lo, Wcls, bcls, (float*)d_out);
}

// Round 4
// 954.490 us; speedup vs baseline: 2.3027x; 1.5942x over previous
//
#include <hip/hip_runtime.h>
#include <hip/hip_bf16.h>

#define Hdim 256
#define Bdim 16
#define Lleaf 4096

typedef unsigned short u16;
typedef __attribute__((ext_vector_type(8))) short short8;
typedef __attribute__((ext_vector_type(4))) float f32x4;

__device__ __forceinline__ u16 f2bf(float x) {
    __hip_bfloat16 b = __float2bfloat16(x);
    return *(u16*)&b;
}
__device__ __forceinline__ float bf2f(u16 u) {
    __hip_bfloat16 b = *(__hip_bfloat16*)&u;
    return __bfloat162float(b);
}
__device__ __forceinline__ float fsig(float x) { return 1.0f / (1.0f + __expf(-x)); }
__device__ __forceinline__ float ftanh(float x) {
    float e = __expf(-2.0f * fabsf(x));
    float t = (1.0f - e) / (1.0f + e);
    return copysignf(t, x);
}

// async global->LDS, 16B per lane. LDS dest = uniform base + lane*16 (HW-forced).
__device__ __forceinline__ void gload_lds16(const u16* gsrc, u16* ldsdst) {
    __builtin_amdgcn_global_load_lds(
        (const __attribute__((address_space(1))) unsigned int*)gsrc,
        (__attribute__((address_space(3))) unsigned int*)ldsdst, 16, 0, 0);
}

// ---------------- weight split+transpose: Wt[g*256+n][k] = W_g[k][n], bf16 hi/lo ----------------
__global__ void split_weights(const float* __restrict__ Wfl, const float* __restrict__ Wfr,
                              const float* __restrict__ Wi,  const float* __restrict__ Wo,
                              const float* __restrict__ Wc,
                              u16* __restrict__ Wthi, u16* __restrict__ Wtlo)
{
    int np = blockIdx.x;            // 0..1279
    int g = np >> 8, n = np & 255;
    const float* W = (g == 0) ? Wfl : (g == 1) ? Wfr : (g == 2) ? Wi : (g == 3) ? Wo : Wc;
    for (int k = threadIdx.x; k < 512; k += 256) {
        float x = W[(size_t)k * Hdim + n];
        u16 hi = f2bf(x);
        u16 lo = f2bf(x - bf2f(hi));
        size_t idx = (size_t)np * 512 + k;
        Wthi[idx] = hi;
        Wtlo[idx] = lo;
    }
}

// ---------------- W_proj split+transpose: Wp[n][k], bf16 hi/lo ----------------
__global__ void split_wp(const float* __restrict__ Wp, u16* __restrict__ Wphi, u16* __restrict__ Wplo)
{
    int n = blockIdx.x;             // 0..255
    int k = threadIdx.x;            // 0..255
    float x = Wp[(size_t)k * Hdim + n];
    u16 hi = f2bf(x);
    u16 lo = f2bf(x - bf2f(hi));
    size_t idx = (size_t)n * 256 + k;
    Wphi[idx] = hi;
    Wplo[idx] = lo;
}

// ---------------- leaf via MFMA: h0 = emb[ids] @ Wp + bp, stored as single bf16 ----------------
// block: 4 waves x 32m = 128m, 64 n-cols (grid.y=4). K=256 in 8 chunks of 32.
// A (emb rows) gathered per-lane fp32, split hi/lo in-register; W pre-split, staged to LDS.
__global__ __launch_bounds__(256, 2) void leaf_mfma(
    const int* __restrict__ ids, const float* __restrict__ emb,
    const u16* __restrict__ Wphi, const u16* __restrict__ Wplo,
    const float* __restrict__ bp, u16* __restrict__ A0hi)
{
    int tid = threadIdx.x;
    int lane = tid & 63, w = tid >> 6;
    int l16 = lane & 15, quad = lane >> 4;
    int m0 = blockIdx.x * 128, n0 = blockIdx.y * 64;

    __shared__ u16 Wlds[8 * 512];   // 8 KB, frag-order: j = nt*2 + t

    const float* aptr[2];
#pragma unroll
    for (int mt = 0; mt < 2; mt++) {
        int m = m0 + w * 32 + mt * 16 + l16;
        aptr[mt] = emb + (size_t)ids[m] * 256;
    }

    f32x4 acc[2][4];
    f32x4 zf = {0.f, 0.f, 0.f, 0.f};
#pragma unroll
    for (int i = 0; i < 2; i++)
#pragma unroll
        for (int j = 0; j < 4; j++) acc[i][j] = zf;

    for (int c = 0; c < 8; c++) {
        int k0 = c * 32;
        // stage W frags (8 x 1KB), 2 instrs per wave
#pragma unroll
        for (int jj = 0; jj < 2; jj++) {
            int j = w * 2 + jj;
            int nt = j >> 1, t = j & 1;
            const u16* src = (t ? Wplo : Wphi) + (size_t)(n0 + nt * 16 + l16) * 256 + k0 + quad * 8;
            gload_lds16(src, &Wlds[j * 512]);
        }
        float4 a0[2], a1[2];
#pragma unroll
        for (int mt = 0; mt < 2; mt++) {
            a0[mt] = *(const float4*)(aptr[mt] + k0 + quad * 8);
            a1[mt] = *(const float4*)(aptr[mt] + k0 + quad * 8 + 4);
        }
        __syncthreads();
        short8 ah[2], al[2];
#pragma unroll
        for (int mt = 0; mt < 2; mt++) {
            float fv[8] = {a0[mt].x, a0[mt].y, a0[mt].z, a0[mt].w,
                           a1[mt].x, a1[mt].y, a1[mt].z, a1[mt].w};
#pragma unroll
            for (int e = 0; e < 8; e++) {
                u16 hv = f2bf(fv[e]);
                u16 lv = f2bf(fv[e] - bf2f(hv));
                ah[mt][e] = (short)hv;
                al[mt][e] = (short)lv;
            }
        }
#pragma unroll
        for (int nt = 0; nt < 4; nt++) {
            short8 bh = *(const short8*)&Wlds[(nt * 2 + 0) * 512 + lane * 8];
            short8 bl = *(const short8*)&Wlds[(nt * 2 + 1) * 512 + lane * 8];
#pragma unroll
            for (int mt = 0; mt < 2; mt++) {
                acc[mt][nt] = __builtin_amdgcn_mfma_f32_16x16x32_bf16(ah[mt], bh, acc[mt][nt], 0, 0, 0);
                acc[mt][nt] = __builtin_amdgcn_mfma_f32_16x16x32_bf16(al[mt], bh, acc[mt][nt], 0, 0, 0);
                acc[mt][nt] = __builtin_amdgcn_mfma_f32_16x16x32_bf16(ah[mt], bl, acc[mt][nt], 0, 0, 0);
            }
        }
        __syncthreads();
    }
    // epilogue: C/D elem r -> row = quad*4 + r, col = l16
#pragma unroll
    for (int mt = 0; mt < 2; mt++)
#pragma unroll
        for (int nt = 0; nt < 4; nt++)
#pragma unroll
            for (int r = 0; r < 4; r++) {
                int m = m0 + w * 32 + mt * 16 + quad * 4 + r;
                int n = n0 + nt * 16 + l16;
                float h = acc[mt][nt][r] + bp[n];
                A0hi[(size_t)(m >> 1) * 512 + (m & 1) * 256 + n] = f2bf(h);
            }
}

// ---------------- fused level: 5 gate GEMMs (MFMA, bf16 split) + LSTM combine ----------------
// block: 4 waves x 32m = 128m, 64 h-cols (grid.y=4), ALL 5 gates per wave (combine wave-local).
// W staged to LDS per 32-k chunk in MFMA-frag order via global_load_lds (conflict-free ds_read).
// A frags load direct global->VGPR. LEAF: A single bf16 (2-term); else A hi/lo (3-term).
template <int LEAF>
__global__ __launch_bounds__(256, 2) void level_mfma2(
    const u16* __restrict__ Ahi, const u16* __restrict__ Alo,
    const float* __restrict__ Cin,
    const u16* __restrict__ Wthi, const u16* __restrict__ Wtlo,
    const float* __restrict__ bfl, const float* __restrict__ bfr,
    const float* __restrict__ bi,  const float* __restrict__ bo,
    const float* __restrict__ bc,
    u16* __restrict__ Aohi, u16* __restrict__ Aolo, float* __restrict__ Cout,
    int M)
{
    int tid = threadIdx.x;
    int lane = tid & 63, w = tid >> 6;
    int l16 = lane & 15, quad = lane >> 4;
    int m0 = blockIdx.x * 128, n0 = blockIdx.y * 64;

    __shared__ u16 Wlds[40 * 512];   // 40 KB, frag-order: j = g*8 + nt*2 + t

    const u16* aph[2];
    const u16* apl[2];
#pragma unroll
    for (int mt = 0; mt < 2; mt++) {
        int ar = min(m0 + w * 32 + mt * 16 + l16, M - 1);
        aph[mt] = Ahi + (size_t)ar * 512 + quad * 8;
        apl[mt] = LEAF ? aph[mt] : (Alo + (size_t)ar * 512 + quad * 8);
    }

    f32x4 acc[5][2][4];
    f32x4 zf = {0.f, 0.f, 0.f, 0.f};
#pragma unroll
    for (int g = 0; g < 5; g++)
#pragma unroll
        for (int i = 0; i < 2; i++)
#pragma unroll
            for (int j = 0; j < 4; j++) acc[g][i][j] = zf;

    for (int c = 0; c < 16; c++) {
        int k0 = c * 32;
        // stage W frags (40 x 1KB), 10 instrs per wave
#pragma unroll
        for (int i = 0; i < 10; i++) {
            int j = w * 10 + i;
            int g = j >> 3, r8 = j & 7;
            int nt = r8 >> 1, t = r8 & 1;
            const u16* src = (t ? Wtlo : Wthi)
                           + (size_t)(g * 256 + n0 + nt * 16 + l16) * 512 + k0 + quad * 8;
            gload_lds16(src, &Wlds[j * 512]);
        }
        short8 ah[2], al[2];
#pragma unroll
        for (int mt = 0; mt < 2; mt++) {
            ah[mt] = *(const short8*)(aph[mt] + k0);
            if (!LEAF) al[mt] = *(const short8*)(apl[mt] + k0);
        }
        __syncthreads();
#pragma unroll
        for (int g = 0; g < 5; g++)
#pragma unroll
            for (int nt = 0; nt < 4; nt++) {
                short8 bh = *(const short8*)&Wlds[((g * 8) + nt * 2 + 0) * 512 + lane * 8];
                short8 bl = *(const short8*)&Wlds[((g * 8) + nt * 2 + 1) * 512 + lane * 8];
#pragma unroll
                for (int mt = 0; mt < 2; mt++) {
                    acc[g][mt][nt] = __builtin_amdgcn_mfma_f32_16x16x32_bf16(ah[mt], bh, acc[g][mt][nt], 0, 0, 0);
                    if (!LEAF)
                        acc[g][mt][nt] = __builtin_amdgcn_mfma_f32_16x16x32_bf16(al[mt], bh, acc[g][mt][nt], 0, 0, 0);
                    acc[g][mt][nt] = __builtin_amdgcn_mfma_f32_16x16x32_bf16(ah[mt], bl, acc[g][mt][nt], 0, 0, 0);
                }
            }
        __syncthreads();
    }

    // epilogue: combine gates -> c, h (hi/lo)
#pragma unroll
    for (int mt = 0; mt < 2; mt++)
#pragma unroll
        for (int r = 0; r < 4; r++) {
            int m = m0 + w * 32 + mt * 16 + quad * 4 + r;
            if (m >= M) continue;
#pragma unroll
            for (int nt = 0; nt < 4; nt++) {
                int n = n0 + nt * 16 + l16;
                float fl = fsig(acc[0][mt][nt][r] + bfl[n]);
                float fr = fsig(acc[1][mt][nt][r] + bfr[n]);
                float ig = fsig(acc[2][mt][nt][r] + bi[n]);
                float og = fsig(acc[3][mt][nt][r] + bo[n]);
                float cc = ftanh(acc[4][mt][nt][r] + bc[n]);
                float cl, cr;
                if (LEAF) {
                    cl = ftanh(bf2f(Ahi[(size_t)m * 512 + n]));
                    cr = ftanh(bf2f(Ahi[(size_t)m * 512 + 256 + n]));
                } else {
                    cl = Cin[(size_t)(2 * m) * 256 + n];
                    cr = Cin[(size_t)(2 * m + 1) * 256 + n];
                }
                float cn = fl * cl + fr * cr + ig * cc;
                Cout[(size_t)m * 256 + n] = cn;
                float h = og * ftanh(cn);
                u16 hh = f2bf(h);
                u16 hl = f2bf(h - bf2f(hh));
                size_t ai = (size_t)(m >> 1) * 512 + (m & 1) * 256 + n;
                Aohi[ai] = hh;
                Aolo[ai] = hl;
            }
        }
}

// ---------------- classifier ----------------
__global__ void classifier_bf(const u16* __restrict__ Ahi, const u16* __restrict__ Alo,
                              const float* __restrict__ Wcls, const float* __restrict__ bcls,
                              float* __restrict__ out)
{
    int t = threadIdx.x;
    if (t < Bdim * 2) {
        int b = t >> 1, cls = t & 1;
        float s = bcls[cls];
        for (int n = 0; n < Hdim; n++) {
            size_t ai = (size_t)(b >> 1) * 512 + (b & 1) * 256 + n;
            float h = bf2f(Ahi[ai]) + bf2f(Alo[ai]);
            s += h * Wcls[(size_t)n * 2 + cls];
        }
        out[t] = s;
    }
}

extern "C" void kernel_launch(void* const* d_in, const int* in_sizes, int n_in,
                              void* d_out, int out_size, void* d_ws, size_t ws_size,
                              hipStream_t stream) {
    const int*   ids  = (const int*)d_in[0];
    const float* emb  = (const float*)d_in[1];
    const float* Wp   = (const float*)d_in[2];
    const float* bp   = (const float*)d_in[3];
    const float* Wfl  = (const float*)d_in[4];
    const float* bfl  = (const float*)d_in[5];
    const float* Wfr  = (const float*)d_in[6];
    const float* bfr  = (const float*)d_in[7];
    const float* Wi   = (const float*)d_in[8];
    const float* bi   = (const float*)d_in[9];
    const float* Wo   = (const float*)d_in[10];
    const float* bo   = (const float*)d_in[11];
    const float* Wc   = (const float*)d_in[12];
    const float* bc   = (const float*)d_in[13];
    const float* Wcls = (const float*)d_in[14];
    const float* bcls = (const float*)d_in[15];

    // ---- ws layout (~100 MiB peak, proven in R3) ----
    // [0, 4MiB): Wt hi/lo (1280x512 each), Wp hi/lo (256x256 each)
    // R1 = base:        32 MiB (leaf A0hi; even-level outs)
    // R2 = base+32MiB:  odd-level outs (L1 out = 64 MiB)
    u16* Wthi = (u16*)d_ws;
    u16* Wtlo = Wthi + (size_t)1280 * 512;
    u16* Wphi = Wtlo + (size_t)1280 * 512;
    u16* Wplo = Wphi + (size_t)256 * 256;
    unsigned char* base = (unsigned char*)d_ws + (4u << 20);
    unsigned char* R1 = base;
    unsigned char* R2 = base + 33554432;

    split_weights<<<1280, 256, 0, stream>>>(Wfl, Wfr, Wi, Wo, Wc, Wthi, Wtlo);
    split_wp<<<256, 256, 0, stream>>>(Wp, Wphi, Wplo);

    int M0 = Bdim * Lleaf;  // 65536 leaves
    leaf_mfma<<<dim3(M0 / 128, 4), 256, 0, stream>>>(ids, emb, Wphi, Wplo, bp, (u16*)R1);

    const u16* Ain_hi = (const u16*)R1;
    const u16* Ain_lo = nullptr;
    const float* Cin = nullptr;

    int lev = 1;
    for (int M = 32768; M >= 16; M >>= 1, lev++) {
        unsigned char* ob = (lev & 1) ? R2 : R1;
        u16* Aohi = (u16*)ob;
        u16* Aolo = Aohi + (size_t)M * 256;
        float* Cout = (float*)(Aohi + (size_t)M * 512);
        dim3 grid((M + 127) / 128, 4);
        if (lev == 1)
            level_mfma2<1><<<grid, 256, 0, stream>>>(Ain_hi, nullptr, nullptr, Wthi, Wtlo,
                                                     bfl, bfr, bi, bo, bc, Aohi, Aolo, Cout, M);
        else
            level_mfma2<0><<<grid, 256, 0, stream>>>(Ain_hi, Ain_lo, Cin, Wthi, Wtlo,
                                                     bfl, bfr, bi, bo, bc, Aohi, Aolo, Cout, M);
        Ain_hi = Aohi; Ain_lo = Aolo; Cin = Cout;
    }

    classifier_bf<<<1, 64, 0, stream>>>(Ain_hi, Ain_lo, Wcls, bcls, (float*)d_out);
}

// Round 5
// 794.768 us; speedup vs baseline: 2.7655x; 1.2010x over previous
//
#include <hip/hip_runtime.h>
#include <hip/hip_bf16.h>

#define Hdim 256
#define Bdim 16
#define Lleaf 4096

typedef unsigned short u16;
typedef __attribute__((ext_vector_type(8))) short short8;
typedef __attribute__((ext_vector_type(4))) float f32x4;

__device__ __forceinline__ u16 f2bf(float x) {
    __hip_bfloat16 b = __float2bfloat16(x);
    return *(u16*)&b;
}
__device__ __forceinline__ float bf2f(u16 u) {
    __hip_bfloat16 b = *(__hip_bfloat16*)&u;
    return __bfloat162float(b);
}
__device__ __forceinline__ float fsig(float x) { return 1.0f / (1.0f + __expf(-x)); }
__device__ __forceinline__ float ftanh(float x) {
    float e = __expf(-2.0f * fabsf(x));
    float t = (1.0f - e) / (1.0f + e);
    return copysignf(t, x);
}

__device__ __forceinline__ void gload_lds16(const u16* gsrc, u16* ldsdst) {
    __builtin_amdgcn_global_load_lds(
        (const __attribute__((address_space(1))) unsigned int*)gsrc,
        (__attribute__((address_space(3))) unsigned int*)ldsdst, 16, 0, 0);
}

// ---------------- weight pack: fragment-major, hi/lo bf16 ----------------
// Wpk[(g*16+ng)*16384 + (c*2+t)*512 + lane*8 + j] = stream_t( W_g[k][n] )
//   n = ng*16 + (lane&15), k = c*32 + (lane>>4)*8 + j
__global__ void pack_weights(const float* __restrict__ Wfl, const float* __restrict__ Wfr,
                             const float* __restrict__ Wi,  const float* __restrict__ Wo,
                             const float* __restrict__ Wc,
                             u16* __restrict__ Wpk)
{
    int blk = blockIdx.x;           // 0..79 = g*16 + ng
    int g = blk >> 4, ng = blk & 15;
    const float* W = (g == 0) ? Wfl : (g == 1) ? Wfr : (g == 2) ? Wi : (g == 3) ? Wo : Wc;
    for (int flat = threadIdx.x; flat < 16384; flat += 256) {
        int c = flat >> 10, rem = flat & 1023;
        int t = rem >> 9, e = rem & 511;
        int lane = e >> 3, j = e & 7;
        int n = ng * 16 + (lane & 15);
        int k = c * 32 + (lane >> 4) * 8 + j;
        float x = W[(size_t)k * Hdim + n];
        u16 hi = f2bf(x);
        u16 v = t ? f2bf(x - bf2f(hi)) : hi;
        Wpk[(size_t)blk * 16384 + flat] = v;
    }
}

// ---------------- W_proj split+transpose (leaf): Wp[n][k], bf16 hi/lo ----------------
__global__ void split_wp(const float* __restrict__ Wp, u16* __restrict__ Wphi, u16* __restrict__ Wplo)
{
    int n = blockIdx.x;
    int k = threadIdx.x;
    float x = Wp[(size_t)k * Hdim + n];
    u16 hi = f2bf(x);
    u16 lo = f2bf(x - bf2f(hi));
    size_t idx = (size_t)n * 256 + k;
    Wphi[idx] = hi;
    Wplo[idx] = lo;
}

// ---------------- leaf via MFMA (unchanged from R4) ----------------
__global__ __launch_bounds__(256, 2) void leaf_mfma(
    const int* __restrict__ ids, const float* __restrict__ emb,
    const u16* __restrict__ Wphi, const u16* __restrict__ Wplo,
    const float* __restrict__ bp, u16* __restrict__ A0hi)
{
    int tid = threadIdx.x;
    int lane = tid & 63, w = tid >> 6;
    int l16 = lane & 15, quad = lane >> 4;
    int m0 = blockIdx.x * 128, n0 = blockIdx.y * 64;

    __shared__ u16 Wlds[8 * 512];

    const float* aptr[2];
#pragma unroll
    for (int mt = 0; mt < 2; mt++) {
        int m = m0 + w * 32 + mt * 16 + l16;
        aptr[mt] = emb + (size_t)ids[m] * 256;
    }

    f32x4 acc[2][4];
    f32x4 zf = {0.f, 0.f, 0.f, 0.f};
#pragma unroll
    for (int i = 0; i < 2; i++)
#pragma unroll
        for (int j = 0; j < 4; j++) acc[i][j] = zf;

    for (int c = 0; c < 8; c++) {
        int k0 = c * 32;
#pragma unroll
        for (int jj = 0; jj < 2; jj++) {
            int j = w * 2 + jj;
            int nt = j >> 1, t = j & 1;
            const u16* src = (t ? Wplo : Wphi) + (size_t)(n0 + nt * 16 + l16) * 256 + k0 + quad * 8;
            gload_lds16(src, &Wlds[j * 512]);
        }
        float4 a0[2], a1[2];
#pragma unroll
        for (int mt = 0; mt < 2; mt++) {
            a0[mt] = *(const float4*)(aptr[mt] + k0 + quad * 8);
            a1[mt] = *(const float4*)(aptr[mt] + k0 + quad * 8 + 4);
        }
        __syncthreads();
        short8 ah[2], al[2];
#pragma unroll
        for (int mt = 0; mt < 2; mt++) {
            float fv[8] = {a0[mt].x, a0[mt].y, a0[mt].z, a0[mt].w,
                           a1[mt].x, a1[mt].y, a1[mt].z, a1[mt].w};
#pragma unroll
            for (int e = 0; e < 8; e++) {
                u16 hv = f2bf(fv[e]);
                u16 lv = f2bf(fv[e] - bf2f(hv));
                ah[mt][e] = (short)hv;
                al[mt][e] = (short)lv;
            }
        }
#pragma unroll
        for (int nt = 0; nt < 4; nt++) {
            short8 bh = *(const short8*)&Wlds[(nt * 2 + 0) * 512 + lane * 8];
            short8 bl = *(const short8*)&Wlds[(nt * 2 + 1) * 512 + lane * 8];
#pragma unroll
            for (int mt = 0; mt < 2; mt++) {
                acc[mt][nt] = __builtin_amdgcn_mfma_f32_16x16x32_bf16(ah[mt], bh, acc[mt][nt], 0, 0, 0);
                acc[mt][nt] = __builtin_amdgcn_mfma_f32_16x16x32_bf16(al[mt], bh, acc[mt][nt], 0, 0, 0);
                acc[mt][nt] = __builtin_amdgcn_mfma_f32_16x16x32_bf16(ah[mt], bl, acc[mt][nt], 0, 0, 0);
            }
        }
        __syncthreads();
    }
#pragma unroll
    for (int mt = 0; mt < 2; mt++)
#pragma unroll
        for (int nt = 0; nt < 4; nt++)
#pragma unroll
            for (int r = 0; r < 4; r++) {
                int m = m0 + w * 32 + mt * 16 + quad * 4 + r;
                int n = n0 + nt * 16 + l16;
                float h = acc[mt][nt][r] + bp[n];
                A0hi[(size_t)(m >> 1) * 512 + (m & 1) * 256 + n] = f2bf(h);
            }
}

// ---------------- fused level, n-split waves ----------------
// Block: 128m x 64n x 5 gates; wave w owns ALL 128m, n-cols [n0+w*16, +16), all gates.
// A staged to LDS (16 frags: (mf,t)); B staged to LDS per-wave (10 frags: (g,t)) from
// fragment-major packed weights (coalesced 1KB loads). Zero B-read redundancy.
template <int LEAF>
__global__ __launch_bounds__(256, 2) void level_mfma3(
    const u16* __restrict__ Ahi, const u16* __restrict__ Alo,
    const float* __restrict__ Cin,
    const u16* __restrict__ Wpk,
    const float* __restrict__ bfl, const float* __restrict__ bfr,
    const float* __restrict__ bi,  const float* __restrict__ bo,
    const float* __restrict__ bc,
    u16* __restrict__ Aohi, u16* __restrict__ Aolo, float* __restrict__ Cout,
    int M)
{
    int tid = threadIdx.x;
    int lane = tid & 63, w = tid >> 6;
    int l16 = lane & 15, quad = lane >> 4;
    int m0 = blockIdx.x * 128, n0 = blockIdx.y * 64;
    int ng = blockIdx.y * 4 + w;            // n-16 group this wave owns

    __shared__ u16 Abuf[16 * 512];          // 16 KB (LEAF uses first 8 frags)
    __shared__ u16 Bbuf[40 * 512];          // 40 KB

    f32x4 acc[5][8];
    f32x4 zf = {0.f, 0.f, 0.f, 0.f};
#pragma unroll
    for (int g = 0; g < 5; g++)
#pragma unroll
        for (int mf = 0; mf < 8; mf++) acc[g][mf] = zf;

    for (int c = 0; c < 16; c++) {
        int k0 = c * 32;
        // ---- stage A ----
        if (LEAF) {
#pragma unroll
            for (int i = 0; i < 2; i++) {
                int mf = w * 2 + i;
                int row = min(m0 + mf * 16 + l16, M - 1);
                gload_lds16(Ahi + (size_t)row * 512 + k0 + quad * 8, &Abuf[mf * 512]);
            }
        } else {
#pragma unroll
            for (int i = 0; i < 4; i++) {
                int j = w * 4 + i;
                int mf = j >> 1, t = j & 1;
                int row = min(m0 + mf * 16 + l16, M - 1);
                const u16* src = (t ? Alo : Ahi) + (size_t)row * 512 + k0 + quad * 8;
                gload_lds16(src, &Abuf[j * 512]);
            }
        }
        // ---- stage B (this wave's 10 frags, coalesced from packed layout) ----
#pragma unroll
        for (int g = 0; g < 5; g++)
#pragma unroll
            for (int t = 0; t < 2; t++) {
                const u16* src = Wpk + (size_t)(g * 16 + ng) * 16384 + (c * 2 + t) * 512 + lane * 8;
                gload_lds16(src, &Bbuf[((w * 5 + g) * 2 + t) * 512]);
            }
        __syncthreads();
        // ---- B frags hoisted, A streamed per mf ----
        short8 bh[5], bl[5];
#pragma unroll
        for (int g = 0; g < 5; g++) {
            bh[g] = *(const short8*)&Bbuf[((w * 5 + g) * 2 + 0) * 512 + lane * 8];
            bl[g] = *(const short8*)&Bbuf[((w * 5 + g) * 2 + 1) * 512 + lane * 8];
        }
#pragma unroll
        for (int mf = 0; mf < 8; mf++) {
            short8 ah, al;
            if (LEAF) {
                ah = *(const short8*)&Abuf[mf * 512 + lane * 8];
            } else {
                ah = *(const short8*)&Abuf[(mf * 2 + 0) * 512 + lane * 8];
                al = *(const short8*)&Abuf[(mf * 2 + 1) * 512 + lane * 8];
            }
#pragma unroll
            for (int g = 0; g < 5; g++) {
                acc[g][mf] = __builtin_amdgcn_mfma_f32_16x16x32_bf16(ah, bh[g], acc[g][mf], 0, 0, 0);
                if (!LEAF)
                    acc[g][mf] = __builtin_amdgcn_mfma_f32_16x16x32_bf16(al, bh[g], acc[g][mf], 0, 0, 0);
                acc[g][mf] = __builtin_amdgcn_mfma_f32_16x16x32_bf16(ah, bl[g], acc[g][mf], 0, 0, 0);
            }
        }
        __syncthreads();
    }

    // ---- epilogue: wave-local combine for its 16 n-cols ----
    int n = n0 + w * 16 + l16;
#pragma unroll
    for (int mf = 0; mf < 8; mf++)
#pragma unroll
        for (int r = 0; r < 4; r++) {
            int m = m0 + mf * 16 + quad * 4 + r;
            if (m >= M) continue;
            float fl = fsig(acc[0][mf][r] + bfl[n]);
            float fr = fsig(acc[1][mf][r] + bfr[n]);
            float ig = fsig(acc[2][mf][r] + bi[n]);
            float og = fsig(acc[3][mf][r] + bo[n]);
            float cc = ftanh(acc[4][mf][r] + bc[n]);
            float cl, cr;
            if (LEAF) {
                cl = ftanh(bf2f(Ahi[(size_t)m * 512 + n]));
                cr = ftanh(bf2f(Ahi[(size_t)m * 512 + 256 + n]));
            } else {
                cl = Cin[(size_t)(2 * m) * 256 + n];
                cr = Cin[(size_t)(2 * m + 1) * 256 + n];
            }
            float cn = fl * cl + fr * cr + ig * cc;
            Cout[(size_t)m * 256 + n] = cn;
            float h = og * ftanh(cn);
            u16 hh = f2bf(h);
            u16 hl = f2bf(h - bf2f(hh));
            size_t ai = (size_t)(m >> 1) * 512 + (m & 1) * 256 + n;
            Aohi[ai] = hh;
            Aolo[ai] = hl;
        }
}

// ---------------- classifier ----------------
__global__ void classifier_bf(const u16* __restrict__ Ahi, const u16* __restrict__ Alo,
                              const float* __restrict__ Wcls, const float* __restrict__ bcls,
                              float* __restrict__ out)
{
    int t = threadIdx.x;
    if (t < Bdim * 2) {
        int b = t >> 1, cls = t & 1;
        float s = bcls[cls];
        for (int n = 0; n < Hdim; n++) {
            size_t ai = (size_t)(b >> 1) * 512 + (b & 1) * 256 + n;
            float h = bf2f(Ahi[ai]) + bf2f(Alo[ai]);
            s += h * Wcls[(size_t)n * 2 + cls];
        }
        out[t] = s;
    }
}

extern "C" void kernel_launch(void* const* d_in, const int* in_sizes, int n_in,
                              void* d_out, int out_size, void* d_ws, size_t ws_size,
                              hipStream_t stream) {
    const int*   ids  = (const int*)d_in[0];
    const float* emb  = (const float*)d_in[1];
    const float* Wp   = (const float*)d_in[2];
    const float* bp   = (const float*)d_in[3];
    const float* Wfl  = (const float*)d_in[4];
    const float* bfl  = (const float*)d_in[5];
    const float* Wfr  = (const float*)d_in[6];
    const float* bfr  = (const float*)d_in[7];
    const float* Wi   = (const float*)d_in[8];
    const float* bi   = (const float*)d_in[9];
    const float* Wo   = (const float*)d_in[10];
    const float* bo   = (const float*)d_in[11];
    const float* Wc   = (const float*)d_in[12];
    const float* bc   = (const float*)d_in[13];
    const float* Wcls = (const float*)d_in[14];
    const float* bcls = (const float*)d_in[15];

    // ws: [0,4MiB) = Wpk (2.62MB) + Wp hi/lo (0.5MB); R1 @4MiB (32MiB); R2 @36MiB
    u16* Wpk  = (u16*)d_ws;
    u16* Wphi = Wpk + (size_t)80 * 16384;
    u16* Wplo = Wphi + (size_t)256 * 256;
    unsigned char* base = (unsigned char*)d_ws + (4u << 20);
    unsigned char* R1 = base;
    unsigned char* R2 = base + 33554432;

    pack_weights<<<80, 256, 0, stream>>>(Wfl, Wfr, Wi, Wo, Wc, Wpk);
    split_wp<<<256, 256, 0, stream>>>(Wp, Wphi, Wplo);

    int M0 = Bdim * Lleaf;
    leaf_mfma<<<dim3(M0 / 128, 4), 256, 0, stream>>>(ids, emb, Wphi, Wplo, bp, (u16*)R1);

    const u16* Ain_hi = (const u16*)R1;
    const u16* Ain_lo = nullptr;
    const float* Cin = nullptr;

    int lev = 1;
    for (int M = 32768; M >= 16; M >>= 1, lev++) {
        unsigned char* ob = (lev & 1) ? R2 : R1;
        u16* Aohi = (u16*)ob;
        u16* Aolo = Aohi + (size_t)M * 256;
        float* Cout = (float*)(Aohi + (size_t)M * 512);
        dim3 grid((M + 127) / 128, 4);
        if (lev == 1)
            level_mfma3<1><<<grid, 256, 0, stream>>>(Ain_hi, nullptr, nullptr, Wpk,
                                                     bfl, bfr, bi, bo, bc, Aohi, Aolo, Cout, M);
        else
            level_mfma3<0><<<grid, 256, 0, stream>>>(Ain_hi, Ain_lo, Cin, Wpk,
                                                     bfl, bfr, bi, bo, bc, Aohi, Aolo, Cout, M);
        Ain_hi = Aohi; Ain_lo = Aolo; Cin = Cout;
    }

    classifier_bf<<<1, 64, 0, stream>>>(Ain_hi, Ain_lo, Wcls, bcls, (float*)d_out);
}